// Round 1
// baseline (463.368 us; speedup 1.0000x reference)
//
#include <hip/hip_runtime.h>

// OrthogonalBasisSelfAttention: B=2, L=2048, D=1024, H=16, DH=64, R=512, NUM_BASIS=6
// out[b,l,h*64+d] = softmax_m( qp[b,h,l,:]·kp[b,h,m,:]/sqrt(512) + bias[h,m-l] + mask[b,m] ) @ V

typedef unsigned short ushort_t;
typedef __attribute__((ext_vector_type(8))) short bf16x8;   // 8 bf16 = 4 VGPR (MFMA A/B frag)
typedef __attribute__((ext_vector_type(4))) float f32x4;    // MFMA C/D frag

__device__ inline f32x4 mfma16(bf16x8 a, bf16x8 b, f32x4 c) {
  return __builtin_amdgcn_mfma_f32_16x16x32_bf16(a, b, c, 0, 0, 0);
}
__device__ inline void load_lds16(const void* g, void* l) {
  __builtin_amdgcn_global_load_lds((const __attribute__((address_space(1))) unsigned int*)g,
                                   (__attribute__((address_space(3))) unsigned int*)l, 16, 0, 0);
}
__device__ inline ushort_t f2bf(float f) {  // round-to-nearest-even
  union { float f; unsigned int u; } v; v.f = f;
  unsigned int u = v.u;
  return (ushort_t)((u + 0x7fffu + ((u >> 16) & 1u)) >> 16);
}

// ---- bias table: tab[h][t], t = (m - q) + 2047 in [0,4094] ----
__global__ void k_bias_tab(const float* __restrict__ coef, float* __restrict__ tab) {
  int h = blockIdx.y;
  int t = blockIdx.x * 256 + threadIdx.x;
  if (t >= 4095) return;
  float x = (float)(t - 2047) * (1.0f / 2047.0f);
  float s = 0.f;
  #pragma unroll
  for (int k = 0; k < 6; k++)
    s += coef[h * 6 + k] * cosf(3.14159265358979323846f * (float)k * x);
  tab[h * 4095 + t] = s;
}

// ---- fp32 -> bf16, 4 per thread ----
__global__ void k_cvt(const float* __restrict__ in, ushort_t* __restrict__ out, int n) {
  int i = (blockIdx.x * 256 + threadIdx.x) * 4;
  if (i >= n) return;
  float4 v = *(const float4*)(in + i);
  unsigned long long pk = (unsigned long long)f2bf(v.x)
                        | ((unsigned long long)f2bf(v.y) << 16)
                        | ((unsigned long long)f2bf(v.z) << 32)
                        | ((unsigned long long)f2bf(v.w) << 48);
  *(unsigned long long*)(out + i) = pk;
}

// ---- proj weight transpose: [16][64][512] f32 -> [16][512][64] bf16 ----
__global__ void k_pwT(const float* __restrict__ pw, ushort_t* __restrict__ out) {
  int h = blockIdx.y;
  int i = blockIdx.x * 256 + threadIdx.x;  // 0..32767
  int d = i >> 9, r = i & 511;
  out[((h << 9) + r) * 64 + d] = f2bf(pw[((h << 6) + d) * 512 + r]);
}

// ---- QKV GEMM: C[4096][3072] = A[4096][1024] @ W[3072][1024]^T + bias ----
// 128x128 tile, BK=32, 4 waves each 64x64 (4x4 16x16x32 MFMA tiles).
__global__ __launch_bounds__(256) void k_gemm_qkv(
    const ushort_t* __restrict__ A, const ushort_t* __restrict__ W,
    const float* __restrict__ bq, const float* __restrict__ bk,
    const float* __restrict__ bv, ushort_t* __restrict__ C) {
  __shared__ ushort_t Asm[128 * 32];  // [row][32], 64B rows, chunk-swizzled c^=(r&3)
  __shared__ ushort_t Bsm[128 * 32];
  const int tid = threadIdx.x, w = tid >> 6, l = tid & 63, g = l >> 4, l15 = l & 15;
  const int mbase = blockIdx.x * 128, nbase = blockIdx.y * 128;
  const int wrow = (w >> 1) * 64, wcol = (w & 1) * 64;
  f32x4 zero4 = {0.f, 0.f, 0.f, 0.f};
  f32x4 acc[4][4];
  #pragma unroll
  for (int i = 0; i < 4; i++)
    #pragma unroll
    for (int j = 0; j < 4; j++) acc[i][j] = zero4;

  for (int kt = 0; kt < 32; ++kt) {
    __syncthreads();
    #pragma unroll
    for (int i = 0; i < 2; i++) {
      int inst = w * 2 + i;            // 8 slabs of 16 rows
      int r = inst * 16 + (l >> 2);    // row in tile
      int cs = (l & 3) ^ (r & 3);      // pre-swizzled source chunk
      load_lds16(A + (size_t)(mbase + r) * 1024 + kt * 32 + cs * 8, &Asm[inst * 512]);
      load_lds16(W + (size_t)(nbase + r) * 1024 + kt * 32 + cs * 8, &Bsm[inst * 512]);
    }
    __syncthreads();
    bf16x8 a[4], bfr[4];
    #pragma unroll
    for (int rt = 0; rt < 4; rt++) {
      int r = wrow + rt * 16 + l15;
      a[rt] = *(const bf16x8*)(&Asm[r * 32 + ((g ^ (r & 3)) << 3)]);
    }
    #pragma unroll
    for (int ct = 0; ct < 4; ct++) {
      int r = wcol + ct * 16 + l15;
      bfr[ct] = *(const bf16x8*)(&Bsm[r * 32 + ((g ^ (r & 3)) << 3)]);
    }
    #pragma unroll
    for (int rt = 0; rt < 4; rt++)
      #pragma unroll
      for (int ct = 0; ct < 4; ct++)
        acc[rt][ct] = mfma16(a[rt], bfr[ct], acc[rt][ct]);
  }
  #pragma unroll
  for (int ct = 0; ct < 4; ct++) {
    int n = nbase + wcol + ct * 16 + l15;
    float bias = (n < 1024) ? bq[n] : (n < 2048 ? bk[n - 1024] : bv[n - 2048]);
    #pragma unroll
    for (int rt = 0; rt < 4; rt++)
      #pragma unroll
      for (int reg = 0; reg < 4; reg++) {
        int m = mbase + wrow + rt * 16 + g * 4 + reg;
        C[(size_t)m * 3072 + n] = f2bf(acc[rt][ct][reg] + bias);
      }
  }
}

// ---- per-head projection: outp[b,h,l,r] = sum_d Q[b*2048+l][off+h*64+d] * pwT[h][r][d] ----
// block: 64 rows x 512 cols; 4 waves each 64x128 (4 row-tiles x 8 col-tiles), K=64 (2 ksteps).
__global__ __launch_bounds__(256) void k_proj(
    const ushort_t* __restrict__ qkv, const ushort_t* __restrict__ pwT,
    ushort_t* __restrict__ outp, int col_off) {
  const int tid = threadIdx.x, w = tid >> 6, l = tid & 63, g = l >> 4, l15 = l & 15;
  const int h = blockIdx.y;
  const int mbase = blockIdx.x * 64;
  const int wcol = w * 128;
  bf16x8 a[4][2];
  #pragma unroll
  for (int rt = 0; rt < 4; rt++) {
    int row = mbase + rt * 16 + l15;
    const ushort_t* p = qkv + (size_t)row * 3072 + col_off + h * 64 + g * 8;
    a[rt][0] = *(const bf16x8*)(p);
    a[rt][1] = *(const bf16x8*)(p + 32);
  }
  f32x4 zero4 = {0.f, 0.f, 0.f, 0.f};
  f32x4 acc[4][8];
  #pragma unroll
  for (int i = 0; i < 4; i++)
    #pragma unroll
    for (int j = 0; j < 8; j++) acc[i][j] = zero4;
  #pragma unroll
  for (int ct = 0; ct < 8; ct++) {
    int n = wcol + ct * 16 + l15;
    const ushort_t* bp = pwT + ((size_t)(h * 512 + n)) * 64 + g * 8;
    bf16x8 b0 = *(const bf16x8*)(bp);
    bf16x8 b1 = *(const bf16x8*)(bp + 32);
    #pragma unroll
    for (int rt = 0; rt < 4; rt++) {
      acc[rt][ct] = mfma16(a[rt][0], b0, acc[rt][ct]);
      acc[rt][ct] = mfma16(a[rt][1], b1, acc[rt][ct]);
    }
  }
  #pragma unroll
  for (int rt = 0; rt < 4; rt++)
    #pragma unroll
    for (int reg = 0; reg < 4; reg++) {
      int m = mbase + rt * 16 + g * 4 + reg;
      int b = m >> 11, lp = m & 2047;
      ushort_t* op = outp + (((size_t)(b * 16 + h)) * 2048 + lp) * 512 + wcol + l15;
      #pragma unroll
      for (int ct = 0; ct < 8; ct++) op[ct * 16] = f2bf(acc[rt][ct][reg]);
    }
}

// ---- flash attention ----
// block = (b,h) x 64 q-rows; 4 waves x 16 q-rows each. kv-blocks of 64.
// qp frags in registers (16 ksteps x bf16x8). kp [64][512] in LDS (XOR-swizzled via
// pre-swizzled global_load_lds source). V transposed into LDS. P via per-wave LDS.
#define NEG_INF -1e30f
__global__ __launch_bounds__(256) void k_attn(
    const ushort_t* __restrict__ qp, const ushort_t* __restrict__ kp,
    const ushort_t* __restrict__ qkv, const float* __restrict__ tab,
    const float* __restrict__ mask, float* __restrict__ out) {
  __shared__ ushort_t kp_sm[64 * 512];   // 64 KB
  __shared__ ushort_t vt_sm[64 * 64];    // 8 KB, Vt[d][m] swizzled
  __shared__ ushort_t p_sm[4][16 * 64];  // 8 KB, per-wave P
  const int tid = threadIdx.x, w = tid >> 6, l = tid & 63, g = l >> 4, l15 = l & 15;
  const int bh = blockIdx.y, b = bh >> 4, h = bh & 15;
  const int qbase = blockIdx.x * 64;

  bf16x8 qf[16];
  {
    const int qrow = qbase + w * 16 + l15;
    const ushort_t* qpr = qp + ((size_t)bh * 2048 + qrow) * 512 + g * 8;
    #pragma unroll
    for (int ks = 0; ks < 16; ks++) qf[ks] = *(const bf16x8*)(qpr + ks * 32);
  }
  f32x4 zero4 = {0.f, 0.f, 0.f, 0.f};
  float mrow[4], lrow[4];
  f32x4 ctx[4];
  #pragma unroll
  for (int i = 0; i < 4; i++) { mrow[i] = NEG_INF; lrow[i] = 0.f; ctx[i] = zero4; }
  const float* tabh = tab + h * 4095 + 2047;
  const float* maskb = mask + b * 2048;
  int qr[4];
  #pragma unroll
  for (int reg = 0; reg < 4; reg++) qr[reg] = qbase + w * 16 + g * 4 + reg;

  for (int kv = 0; kv < 32; kv++) {
    const int kvbase = kv * 64;
    {  // stage kp rows w*16..w*16+15; LDS chunk c holds global chunk c^(r&7)
      const ushort_t* kpb = kp + ((size_t)bh * 2048 + kvbase) * 512;
      #pragma unroll
      for (int i = 0; i < 16; i++) {
        int r = w * 16 + i;
        load_lds16(kpb + (size_t)r * 512 + ((l ^ (r & 7)) << 3), &kp_sm[r * 512]);
      }
    }
    {  // stage V transposed: Vt[d][m], swizzled chunk' = (m>>3)^(d&7)
      const ushort_t* vb = qkv + ((size_t)(b * 2048 + kvbase)) * 3072 + 2048 + h * 64;
      #pragma unroll
      for (int i = 0; i < 2; i++) {
        int c = tid * 2 + i;
        int m = c >> 3, ch = c & 7;
        bf16x8 v = *(const bf16x8*)(vb + (size_t)m * 3072 + ch * 8);
        #pragma unroll
        for (int j = 0; j < 8; j++) {
          int d = ch * 8 + j;
          vt_sm[d * 64 + ((((m >> 3) ^ (d & 7)) << 3) + (m & 7))] = ((const ushort_t*)&v)[j];
        }
      }
    }
    __syncthreads();
    // S = qp . kp^T
    f32x4 S[4];
    #pragma unroll
    for (int ct = 0; ct < 4; ct++) S[ct] = zero4;
    #pragma unroll
    for (int ks = 0; ks < 16; ks++) {
      #pragma unroll
      for (int ct = 0; ct < 4; ct++) {
        int m = ct * 16 + l15;
        int cidx = (4 * ks + g) ^ (m & 7);
        bf16x8 bf = *(const bf16x8*)(&kp_sm[m * 512 + cidx * 8]);
        S[ct] = mfma16(qf[ks], bf, S[ct]);
      }
    }
    // softmax (online)
    float p[4][4], rm[4];
    #pragma unroll
    for (int reg = 0; reg < 4; reg++) rm[reg] = NEG_INF;
    #pragma unroll
    for (int ct = 0; ct < 4; ct++) {
      int m = kvbase + ct * 16 + l15;
      float mv = maskb[m];
      const float* tq = tabh + m;
      #pragma unroll
      for (int reg = 0; reg < 4; reg++) {
        float sv = S[ct][reg] * 0.044194173824159216f + tq[-qr[reg]] + mv;
        p[ct][reg] = sv;
        rm[reg] = fmaxf(rm[reg], sv);
      }
    }
    #pragma unroll
    for (int off = 1; off < 16; off <<= 1)
      #pragma unroll
      for (int reg = 0; reg < 4; reg++) rm[reg] = fmaxf(rm[reg], __shfl_xor(rm[reg], off));
    float corr[4], rs[4];
    #pragma unroll
    for (int reg = 0; reg < 4; reg++) {
      float mn = fmaxf(mrow[reg], rm[reg]);
      corr[reg] = __expf(mrow[reg] - mn);
      mrow[reg] = mn;
      rs[reg] = 0.f;
    }
    #pragma unroll
    for (int ct = 0; ct < 4; ct++)
      #pragma unroll
      for (int reg = 0; reg < 4; reg++) {
        float e = __expf(p[ct][reg] - mrow[reg]);
        p[ct][reg] = e;
        rs[reg] += e;
      }
    #pragma unroll
    for (int off = 1; off < 16; off <<= 1)
      #pragma unroll
      for (int reg = 0; reg < 4; reg++) rs[reg] += __shfl_xor(rs[reg], off);
    #pragma unroll
    for (int reg = 0; reg < 4; reg++) lrow[reg] = lrow[reg] * corr[reg] + rs[reg];
    #pragma unroll
    for (int dt = 0; dt < 4; dt++)
      #pragma unroll
      for (int reg = 0; reg < 4; reg++) ctx[dt][reg] *= corr[reg];
    // write P (per-wave LDS, bf16, swizzled)
    ushort_t* pw_sm = &p_sm[w][0];
    #pragma unroll
    for (int ct = 0; ct < 4; ct++) {
      int m = ct * 16 + l15;
      #pragma unroll
      for (int reg = 0; reg < 4; reg++) {
        int r = g * 4 + reg;
        pw_sm[r * 64 + ((((m >> 3) ^ (r & 7)) << 3) + (m & 7))] = f2bf(p[ct][reg]);
      }
    }
    // PV: ctx[r][d] += sum_m P[r][m] V[m][d]
    #pragma unroll
    for (int ks = 0; ks < 2; ks++) {
      int ca = (4 * ks + g) ^ (l15 & 7);
      bf16x8 pa = *(const bf16x8*)(&pw_sm[l15 * 64 + ca * 8]);
      #pragma unroll
      for (int dt = 0; dt < 4; dt++) {
        int d = dt * 16 + l15;
        int cb = (4 * ks + g) ^ (d & 7);
        bf16x8 vfr = *(const bf16x8*)(&vt_sm[d * 64 + cb * 8]);
        ctx[dt] = mfma16(pa, vfr, ctx[dt]);
      }
    }
    __syncthreads();
  }
  #pragma unroll
  for (int reg = 0; reg < 4; reg++) {
    float inv = 1.0f / lrow[reg];
    float* op = out + ((size_t)(b * 2048 + qr[reg])) * 1024 + h * 64 + l15;
    #pragma unroll
    for (int dt = 0; dt < 4; dt++) op[dt * 16] = ctx[dt][reg] * inv;
  }
}

extern "C" void kernel_launch(void* const* d_in, const int* in_sizes, int n_in,
                              void* d_out, int out_size, void* d_ws, size_t ws_size,
                              hipStream_t stream) {
  const float* hidden = (const float*)d_in[0];
  const float* maskp  = (const float*)d_in[1];
  const float* Wq     = (const float*)d_in[2];
  const float* bq     = (const float*)d_in[3];
  const float* Wk     = (const float*)d_in[4];
  const float* bk     = (const float*)d_in[5];
  const float* Wv     = (const float*)d_in[6];
  const float* bv     = (const float*)d_in[7];
  const float* qpw    = (const float*)d_in[8];
  const float* kpw    = (const float*)d_in[9];
  const float* coef   = (const float*)d_in[10];

  char* ws = (char*)d_ws;
  float*    tab  = (float*)(ws);                      // 16*4095*4      = 262,080 -> 262,144
  ushort_t* hb   = (ushort_t*)(ws + 262144);          // 4096*1024*2    = 8,388,608
  ushort_t* w3   = (ushort_t*)(ws + 8650752);         // 3072*1024*2    = 6,291,456
  ushort_t* qpwT = (ushort_t*)(ws + 14942208);        // 16*512*64*2    = 1,048,576
  ushort_t* kpwT = (ushort_t*)(ws + 15990784);        // 1,048,576
  ushort_t* qkv  = (ushort_t*)(ws + 17039360);        // 4096*3072*2    = 25,165,824
  ushort_t* qpb  = (ushort_t*)(ws + 42205184);        // 32*2048*512*2  = 67,108,864
  ushort_t* kpb  = (ushort_t*)(ws + 109314048);       // 67,108,864 (end 176,422,912)

  k_bias_tab<<<dim3(16, 16), 256, 0, stream>>>(coef, tab);
  k_cvt<<<4096, 256, 0, stream>>>(hidden, hb, 4194304);
  k_cvt<<<1024, 256, 0, stream>>>(Wq, w3, 1048576);
  k_cvt<<<1024, 256, 0, stream>>>(Wk, w3 + 1048576, 1048576);
  k_cvt<<<1024, 256, 0, stream>>>(Wv, w3 + 2097152, 1048576);
  k_pwT<<<dim3(128, 16), 256, 0, stream>>>(qpw, qpwT);
  k_pwT<<<dim3(128, 16), 256, 0, stream>>>(kpw, kpwT);
  k_gemm_qkv<<<dim3(32, 24), 256, 0, stream>>>(hb, w3, bq, bk, bv, qkv);
  k_proj<<<dim3(64, 16), 256, 0, stream>>>(qkv, qpwT, qpb, 0);
  k_proj<<<dim3(64, 16), 256, 0, stream>>>(qkv, kpwT, kpb, 1024);
  k_attn<<<dim3(32, 32), 256, 0, stream>>>(qpb, kpb, qkv, tab, maskp, (float*)d_out);
}

// Round 2
// 303.700 us; speedup vs baseline: 1.5257x; 1.5257x over previous
//
#include <hip/hip_runtime.h>

// OrthogonalBasisSelfAttention: B=2, L=2048, D=1024, H=16, DH=64, R=512, NUM_BASIS=6
// out[b,l,h*64+d] = softmax_m( qp[b,h,l,:]·kp[b,h,m,:]/sqrt(512) + bias[h,m-l] + mask[b,m] ) @ V

typedef unsigned short ushort_t;
typedef __attribute__((ext_vector_type(8))) short bf16x8;   // 8 bf16 = 4 VGPR (MFMA A/B frag)
typedef __attribute__((ext_vector_type(4))) float f32x4;    // MFMA C/D frag

__device__ inline f32x4 mfma16(bf16x8 a, bf16x8 b, f32x4 c) {
  return __builtin_amdgcn_mfma_f32_16x16x32_bf16(a, b, c, 0, 0, 0);
}
__device__ inline void load_lds16(const void* g, void* l) {
  __builtin_amdgcn_global_load_lds((const __attribute__((address_space(1))) unsigned int*)g,
                                   (__attribute__((address_space(3))) unsigned int*)l, 16, 0, 0);
}
__device__ inline ushort_t f2bf(float f) {  // round-to-nearest-even
  union { float f; unsigned int u; } v; v.f = f;
  unsigned int u = v.u;
  return (ushort_t)((u + 0x7fffu + ((u >> 16) & 1u)) >> 16);
}
__device__ inline unsigned cvt_pk_bf16(float lo, float hi) {
  unsigned r;
  asm("v_cvt_pk_bf16_f32 %0, %1, %2" : "=v"(r) : "v"(lo), "v"(hi));
  return r;
}

// ---- bias table: tab[h][t], t = (m - q) + 2047 in [0,4094] ----
__global__ void k_bias_tab(const float* __restrict__ coef, float* __restrict__ tab) {
  int h = blockIdx.y;
  int t = blockIdx.x * 256 + threadIdx.x;
  if (t >= 4095) return;
  float x = (float)(t - 2047) * (1.0f / 2047.0f);
  float s = 0.f;
  #pragma unroll
  for (int k = 0; k < 6; k++)
    s += coef[h * 6 + k] * cosf(3.14159265358979323846f * (float)k * x);
  tab[h * 4095 + t] = s;
}

// ---- fp32 -> bf16, 4 per thread ----
__global__ void k_cvt(const float* __restrict__ in, ushort_t* __restrict__ out, int n) {
  int i = (blockIdx.x * 256 + threadIdx.x) * 4;
  if (i >= n) return;
  float4 v = *(const float4*)(in + i);
  unsigned long long pk = (unsigned long long)f2bf(v.x)
                        | ((unsigned long long)f2bf(v.y) << 16)
                        | ((unsigned long long)f2bf(v.z) << 32)
                        | ((unsigned long long)f2bf(v.w) << 48);
  *(unsigned long long*)(out + i) = pk;
}

// ---- proj weight transpose: [16][64][512] f32 -> [16][512][64] bf16 ----
__global__ void k_pwT(const float* __restrict__ pw, ushort_t* __restrict__ out) {
  int h = blockIdx.y;
  int i = blockIdx.x * 256 + threadIdx.x;  // 0..32767
  int d = i >> 9, r = i & 511;
  out[((h << 9) + r) * 64 + d] = f2bf(pw[((h << 6) + d) * 512 + r]);
}

// ---- V transpose: qkv V-cols -> vT[bh][64 d][2048 m] bf16 ----
__global__ void k_vT(const ushort_t* __restrict__ qkv, ushort_t* __restrict__ vT) {
  int bh = blockIdx.y, b = bh >> 4, h = bh & 15;
  int d = threadIdx.x >> 2;                       // 0..63
  int mc = blockIdx.x * 4 + (threadIdx.x & 3);    // 0..255
  int m0 = mc * 8;
  const ushort_t* src = qkv + ((size_t)(b * 2048 + m0)) * 3072 + 2048 + h * 64 + d;
  bf16x8 r;
  #pragma unroll
  for (int j = 0; j < 8; j++) r[j] = (short)src[(size_t)j * 3072];
  *(bf16x8*)(vT + ((size_t)(bh * 64 + d)) * 2048 + m0) = r;
}

// ---- QKV GEMM: C[4096][3072] = A[4096][1024] @ W[3072][1024]^T + bias ----
__global__ __launch_bounds__(256) void k_gemm_qkv(
    const ushort_t* __restrict__ A, const ushort_t* __restrict__ W,
    const float* __restrict__ bq, const float* __restrict__ bk,
    const float* __restrict__ bv, ushort_t* __restrict__ C) {
  __shared__ ushort_t Asm[128 * 32];
  __shared__ ushort_t Bsm[128 * 32];
  const int tid = threadIdx.x, w = tid >> 6, l = tid & 63, g = l >> 4, l15 = l & 15;
  const int mbase = blockIdx.x * 128, nbase = blockIdx.y * 128;
  const int wrow = (w >> 1) * 64, wcol = (w & 1) * 64;
  f32x4 zero4 = {0.f, 0.f, 0.f, 0.f};
  f32x4 acc[4][4];
  #pragma unroll
  for (int i = 0; i < 4; i++)
    #pragma unroll
    for (int j = 0; j < 4; j++) acc[i][j] = zero4;

  for (int kt = 0; kt < 32; ++kt) {
    __syncthreads();
    #pragma unroll
    for (int i = 0; i < 2; i++) {
      int inst = w * 2 + i;
      int r = inst * 16 + (l >> 2);
      int cs = (l & 3) ^ (r & 3);
      load_lds16(A + (size_t)(mbase + r) * 1024 + kt * 32 + cs * 8, &Asm[inst * 512]);
      load_lds16(W + (size_t)(nbase + r) * 1024 + kt * 32 + cs * 8, &Bsm[inst * 512]);
    }
    __syncthreads();
    bf16x8 a[4], bfr[4];
    #pragma unroll
    for (int rt = 0; rt < 4; rt++) {
      int r = wrow + rt * 16 + l15;
      a[rt] = *(const bf16x8*)(&Asm[r * 32 + ((g ^ (r & 3)) << 3)]);
    }
    #pragma unroll
    for (int ct = 0; ct < 4; ct++) {
      int r = wcol + ct * 16 + l15;
      bfr[ct] = *(const bf16x8*)(&Bsm[r * 32 + ((g ^ (r & 3)) << 3)]);
    }
    #pragma unroll
    for (int rt = 0; rt < 4; rt++)
      #pragma unroll
      for (int ct = 0; ct < 4; ct++)
        acc[rt][ct] = mfma16(a[rt], bfr[ct], acc[rt][ct]);
  }
  #pragma unroll
  for (int ct = 0; ct < 4; ct++) {
    int n = nbase + wcol + ct * 16 + l15;
    float bias = (n < 1024) ? bq[n] : (n < 2048 ? bk[n - 1024] : bv[n - 2048]);
    #pragma unroll
    for (int rt = 0; rt < 4; rt++)
      #pragma unroll
      for (int reg = 0; reg < 4; reg++) {
        int m = mbase + wrow + rt * 16 + g * 4 + reg;
        C[(size_t)m * 3072 + n] = f2bf(acc[rt][ct][reg] + bias);
      }
  }
}

// ---- per-head projection ----
__global__ __launch_bounds__(256) void k_proj(
    const ushort_t* __restrict__ qkv, const ushort_t* __restrict__ pwT,
    ushort_t* __restrict__ outp, int col_off) {
  const int tid = threadIdx.x, w = tid >> 6, l = tid & 63, g = l >> 4, l15 = l & 15;
  const int h = blockIdx.y;
  const int mbase = blockIdx.x * 64;
  const int wcol = w * 128;
  bf16x8 a[4][2];
  #pragma unroll
  for (int rt = 0; rt < 4; rt++) {
    int row = mbase + rt * 16 + l15;
    const ushort_t* p = qkv + (size_t)row * 3072 + col_off + h * 64 + g * 8;
    a[rt][0] = *(const bf16x8*)(p);
    a[rt][1] = *(const bf16x8*)(p + 32);
  }
  f32x4 zero4 = {0.f, 0.f, 0.f, 0.f};
  f32x4 acc[4][8];
  #pragma unroll
  for (int i = 0; i < 4; i++)
    #pragma unroll
    for (int j = 0; j < 8; j++) acc[i][j] = zero4;
  #pragma unroll
  for (int ct = 0; ct < 8; ct++) {
    int n = wcol + ct * 16 + l15;
    const ushort_t* bp = pwT + ((size_t)(h * 512 + n)) * 64 + g * 8;
    bf16x8 b0 = *(const bf16x8*)(bp);
    bf16x8 b1 = *(const bf16x8*)(bp + 32);
    #pragma unroll
    for (int rt = 0; rt < 4; rt++) {
      acc[rt][ct] = mfma16(a[rt][0], b0, acc[rt][ct]);
      acc[rt][ct] = mfma16(a[rt][1], b1, acc[rt][ct]);
    }
  }
  #pragma unroll
  for (int rt = 0; rt < 4; rt++)
    #pragma unroll
    for (int reg = 0; reg < 4; reg++) {
      int m = mbase + rt * 16 + g * 4 + reg;
      int b = m >> 11, lp = m & 2047;
      ushort_t* op = outp + (((size_t)(b * 16 + h)) * 2048 + lp) * 512 + wcol + l15;
      #pragma unroll
      for (int ct = 0; ct < 8; ct++) op[ct * 16] = f2bf(acc[rt][ct][reg]);
    }
}

// ---- flash attention: 8 waves x 32 q-rows = 256 q-rows/block, KVB=32, dbuf DMA staging ----
#define NEG_INF -1e30f
#define FENCE() asm volatile("" ::: "memory")
__global__ __launch_bounds__(512, 2) void k_attn(
    const ushort_t* __restrict__ qp, const ushort_t* __restrict__ kp,
    const ushort_t* __restrict__ vT, const float* __restrict__ tab,
    const float* __restrict__ mask, float* __restrict__ out) {
  __shared__ ushort_t kp_sm[2][32][512];   // 64 KB, phys chunk c holds global chunk c^(m&7)
  __shared__ ushort_t vt_sm[2][64][32];    // 8 KB,  phys chunk c holds global chunk c^((d>>1)&3)
  __shared__ ushort_t p_sm[8][2][16][32];  // 16 KB, per-wave P, chunk ^ ((l15>>1)&3)
  const int tid = threadIdx.x, w = tid >> 6, l = tid & 63, g = l >> 4, l15 = l & 15;
  // XCD-chunked mapping: 256 blocks, 1/CU; each XCD owns 4 bh
  const int bid = blockIdx.x, xcd = bid & 7, slot = bid >> 3;
  const int bh = xcd * 4 + (slot & 3), qb = slot >> 2;
  const int b = bh >> 4, h = bh & 15;
  const int wrow = qb * 256 + w * 32;

  const ushort_t* kp_bh = kp + (size_t)bh * 2048 * 512;
  const ushort_t* vT_bh = vT + (size_t)bh * 64 * 2048;
  const float* tabh = tab + h * 4095 + 2047;
  const float* maskb = mask + b * 2048;

  // qf: 2 sets x 16 k-frags (q-rows wrow+l15, wrow+16+l15)
  bf16x8 qf[2][16];
  #pragma unroll
  for (int s = 0; s < 2; s++) {
    const ushort_t* qpr = qp + ((size_t)bh * 2048 + wrow + s * 16 + l15) * 512 + g * 8;
    #pragma unroll
    for (int ks = 0; ks < 16; ks++) qf[s][ks] = *(const bf16x8*)(qpr + ks * 32);
  }

  f32x4 zero4 = {0.f, 0.f, 0.f, 0.f};
  f32x4 ctx[2][4];
  float mrow[2], lrow[2];
  #pragma unroll
  for (int s = 0; s < 2; s++) {
    mrow[s] = NEG_INF; lrow[s] = 0.f;
    #pragma unroll
    for (int dt = 0; dt < 4; dt++) ctx[s][dt] = zero4;
  }

  auto stage = [&](int t, int bi) {
    int kvb = t * 32;
    #pragma unroll
    for (int ii = 0; ii < 4; ii++) {
      int m = w * 4 + ii;
      load_lds16(kp_bh + ((size_t)(kvb + m)) * 512 + ((l ^ (m & 7)) << 3), &kp_sm[bi][m][0]);
    }
    if (w < 4) {
      int d = w * 16 + (l >> 2), c = l & 3;
      load_lds16(vT_bh + (size_t)d * 2048 + kvb + ((c ^ ((d >> 1) & 3)) << 3), &vt_sm[bi][w * 16][0]);
    }
  };

  stage(0, 0);
  for (int t = 0; t < 64; t++) {
    const int bi = t & 1;
    const int kvb = t * 32;
    if (t < 63) {
      stage(t + 1, bi ^ 1);
      if (w < 4) { asm volatile("s_waitcnt vmcnt(5)" ::: "memory"); }
      else       { asm volatile("s_waitcnt vmcnt(4)" ::: "memory"); }
    } else {
      asm volatile("s_waitcnt vmcnt(0)" ::: "memory");
    }
    __builtin_amdgcn_s_barrier();
    FENCE();

    // bias+mask pre-terms (latency hidden under QK^T)
    float pre[2][2][4];
    #pragma unroll
    for (int mt = 0; mt < 2; mt++) {
      float4 mk = *(const float4*)(maskb + kvb + mt * 16 + g * 4);
      #pragma unroll
      for (int s = 0; s < 2; s++) {
        const float* tq = tabh + kvb - (wrow + s * 16 + l15) + mt * 16 + g * 4;
        pre[s][mt][0] = tq[0] + mk.x;
        pre[s][mt][1] = tq[1] + mk.y;
        pre[s][mt][2] = tq[2] + mk.z;
        pre[s][mt][3] = tq[3] + mk.w;
      }
    }

    // QK^T (swapped): ST[s][mt] lane holds S[r=l15(+16s)][m=kvb+mt*16+g*4+reg]
    f32x4 ST[2][2];
    #pragma unroll
    for (int s = 0; s < 2; s++) { ST[s][0] = zero4; ST[s][1] = zero4; }
    #pragma unroll
    for (int ks = 0; ks < 16; ks++) {
      #pragma unroll
      for (int mt = 0; mt < 2; mt++) {
        bf16x8 af = *(const bf16x8*)(&kp_sm[bi][mt * 16 + l15][((ks * 4 + g) ^ (l15 & 7)) << 3]);
        ST[0][mt] = mfma16(af, qf[0][ks], ST[0][mt]);
        ST[1][mt] = mfma16(af, qf[1][ks], ST[1][mt]);
      }
    }

    // online softmax, per lane (each lane owns one q-row per set)
    #pragma unroll
    for (int s = 0; s < 2; s++) {
      float sv[2][4];
      float rm = NEG_INF;
      #pragma unroll
      for (int mt = 0; mt < 2; mt++)
        #pragma unroll
        for (int reg = 0; reg < 4; reg++) {
          sv[mt][reg] = fmaf(ST[s][mt][reg], 0.044194173824159216f, pre[s][mt][reg]);
          rm = fmaxf(rm, sv[mt][reg]);
        }
      rm = fmaxf(rm, __shfl_xor(rm, 16));
      rm = fmaxf(rm, __shfl_xor(rm, 32));
      float mn = fmaxf(mrow[s], rm);
      float corr = __expf(mrow[s] - mn);
      mrow[s] = mn;
      float pv[2][4], rs = 0.f;
      #pragma unroll
      for (int mt = 0; mt < 2; mt++)
        #pragma unroll
        for (int reg = 0; reg < 4; reg++) {
          pv[mt][reg] = __expf(sv[mt][reg] - mn);
          rs += pv[mt][reg];
        }
      rs += __shfl_xor(rs, 16);
      rs += __shfl_xor(rs, 32);
      lrow[s] = lrow[s] * corr + rs;
      #pragma unroll
      for (int dt = 0; dt < 4; dt++)
        #pragma unroll
        for (int e = 0; e < 4; e++) ctx[s][dt][e] *= corr;
      // P -> bf16, one b64 write per mt (chunk-XOR swizzled)
      #pragma unroll
      for (int mt = 0; mt < 2; mt++) {
        unsigned w0 = cvt_pk_bf16(pv[mt][0], pv[mt][1]);
        unsigned w1 = cvt_pk_bf16(pv[mt][2], pv[mt][3]);
        int ch = (mt * 2 + (g >> 1)) ^ ((l15 >> 1) & 3);
        *(uint2*)((ushort_t*)&p_sm[w][s][l15][0] + ch * 8 + (g & 1) * 4) = make_uint2(w0, w1);
      }
    }

    // PV: ctx[s][dt] += V^T-frag x P-frag
    #pragma unroll
    for (int s = 0; s < 2; s++) {
      bf16x8 pf = *(const bf16x8*)(&p_sm[w][s][l15][(g ^ ((l15 >> 1) & 3)) << 3]);
      #pragma unroll
      for (int dt = 0; dt < 4; dt++) {
        int d = dt * 16 + l15;
        bf16x8 vf = *(const bf16x8*)(&vt_sm[bi][d][(g ^ ((d >> 1) & 3)) << 3]);
        ctx[s][dt] = mfma16(vf, pf, ctx[s][dt]);
      }
    }

    FENCE();
    __builtin_amdgcn_s_barrier();
    FENCE();
  }

  #pragma unroll
  for (int s = 0; s < 2; s++) {
    float inv = 1.0f / lrow[s];
    int r = wrow + s * 16 + l15;
    float* op = out + ((size_t)(b * 2048 + r)) * 1024 + h * 64 + g * 4;
    #pragma unroll
    for (int dt = 0; dt < 4; dt++) {
      float4 o = {ctx[s][dt][0] * inv, ctx[s][dt][1] * inv, ctx[s][dt][2] * inv, ctx[s][dt][3] * inv};
      *(float4*)(op + dt * 16) = o;
    }
  }
}

extern "C" void kernel_launch(void* const* d_in, const int* in_sizes, int n_in,
                              void* d_out, int out_size, void* d_ws, size_t ws_size,
                              hipStream_t stream) {
  const float* hidden = (const float*)d_in[0];
  const float* maskp  = (const float*)d_in[1];
  const float* Wq     = (const float*)d_in[2];
  const float* bq     = (const float*)d_in[3];
  const float* Wk     = (const float*)d_in[4];
  const float* bk     = (const float*)d_in[5];
  const float* Wv     = (const float*)d_in[6];
  const float* bv     = (const float*)d_in[7];
  const float* qpw    = (const float*)d_in[8];
  const float* kpw    = (const float*)d_in[9];
  const float* coef   = (const float*)d_in[10];

  char* ws = (char*)d_ws;
  float*    tab  = (float*)(ws);                      // 262,144
  ushort_t* hb   = (ushort_t*)(ws + 262144);          // 8,388,608 (reused as vT after GEMM)
  ushort_t* w3   = (ushort_t*)(ws + 8650752);         // 6,291,456
  ushort_t* qpwT = (ushort_t*)(ws + 14942208);        // 1,048,576
  ushort_t* kpwT = (ushort_t*)(ws + 15990784);        // 1,048,576
  ushort_t* qkv  = (ushort_t*)(ws + 17039360);        // 25,165,824
  ushort_t* qpb  = (ushort_t*)(ws + 42205184);        // 67,108,864
  ushort_t* kpb  = (ushort_t*)(ws + 109314048);       // 67,108,864 (end 176,422,912)
  ushort_t* vTb  = hb;                                // 8 MB, hb is dead after GEMM

  k_bias_tab<<<dim3(16, 16), 256, 0, stream>>>(coef, tab);
  k_cvt<<<4096, 256, 0, stream>>>(hidden, hb, 4194304);
  k_cvt<<<1024, 256, 0, stream>>>(Wq, w3, 1048576);
  k_cvt<<<1024, 256, 0, stream>>>(Wk, w3 + 1048576, 1048576);
  k_cvt<<<1024, 256, 0, stream>>>(Wv, w3 + 2097152, 1048576);
  k_pwT<<<dim3(128, 16), 256, 0, stream>>>(qpw, qpwT);
  k_pwT<<<dim3(128, 16), 256, 0, stream>>>(kpw, kpwT);
  k_gemm_qkv<<<dim3(32, 24), 256, 0, stream>>>(hb, w3, bq, bk, bv, qkv);
  k_vT<<<dim3(64, 32), 256, 0, stream>>>(qkv, vTb);
  k_proj<<<dim3(64, 16), 256, 0, stream>>>(qkv, qpwT, qpb, 0);
  k_proj<<<dim3(64, 16), 256, 0, stream>>>(qkv, kpwT, kpb, 1024);
  k_attn<<<dim3(256), 512, 0, stream>>>(qpb, kpb, vTb, tab, maskp, (float*)d_out);
}

// Round 4
// 179.909 us; speedup vs baseline: 2.5756x; 1.6881x over previous
//
#include <hip/hip_runtime.h>

// OrthogonalBasisSelfAttention: B=2, L=2048, D=1024, H=16, DH=64, R=512, NUM_BASIS=6
// scores = qp.kp^T/sqrt(R) = q.(Wqp Wkp^T/sqrt(R)).k^T  -> fold A_h = Wqp Wkp^T/sqrt(R)
// into Wq' = A_h^T Wq so the QKV GEMM emits qt directly; then S = qt.k^T with K=64.

typedef unsigned short ushort_t;
typedef __attribute__((ext_vector_type(8))) short bf16x8;   // 8 bf16 = 4 VGPR (MFMA A/B frag)
typedef __attribute__((ext_vector_type(4))) float f32x4;    // MFMA C/D frag

__device__ inline f32x4 mfma16(bf16x8 a, bf16x8 b, f32x4 c) {
  return __builtin_amdgcn_mfma_f32_16x16x32_bf16(a, b, c, 0, 0, 0);
}
__device__ inline void load_lds16(const void* g, void* l) {
  __builtin_amdgcn_global_load_lds((const __attribute__((address_space(1))) unsigned int*)g,
                                   (__attribute__((address_space(3))) unsigned int*)l, 16, 0, 0);
}
__device__ inline ushort_t f2bf(float f) {  // round-to-nearest-even
  union { float f; unsigned int u; } v; v.f = f;
  unsigned int u = v.u;
  return (ushort_t)((u + 0x7fffu + ((u >> 16) & 1u)) >> 16);
}
__device__ inline unsigned cvt_pk_bf16(float lo, float hi) {
  unsigned r;
  asm("v_cvt_pk_bf16_f32 %0, %1, %2" : "=v"(r) : "v"(lo), "v"(hi));
  return r;
}

// ---- bias table: tab[h][t], t = (m - q) + 2047 in [0,4094] ----
__global__ void k_bias_tab(const float* __restrict__ coef, float* __restrict__ tab) {
  int h = blockIdx.y;
  int t = blockIdx.x * 256 + threadIdx.x;
  if (t >= 4095) return;
  float x = (float)(t - 2047) * (1.0f / 2047.0f);
  float s = 0.f;
  #pragma unroll
  for (int k = 0; k < 6; k++)
    s += coef[h * 6 + k] * cosf(3.14159265358979323846f * (float)k * x);
  tab[h * 4095 + t] = s;
}

// ---- fp32 -> bf16, 4 per thread ----
__global__ void k_cvt(const float* __restrict__ in, ushort_t* __restrict__ out, int n) {
  int i = (blockIdx.x * 256 + threadIdx.x) * 4;
  if (i >= n) return;
  float4 v = *(const float4*)(in + i);
  unsigned long long pk = (unsigned long long)f2bf(v.x)
                        | ((unsigned long long)f2bf(v.y) << 16)
                        | ((unsigned long long)f2bf(v.z) << 32)
                        | ((unsigned long long)f2bf(v.w) << 48);
  *(unsigned long long*)(out + i) = pk;
}

// ---- A_h[h][d][d'] = sum_r Wqp[h][d][r] * Wkp[h][d'][r] / sqrt(512), fp32 ----
__global__ void k_ah(const float* __restrict__ qpw, const float* __restrict__ kpw,
                     float* __restrict__ Ah) {
  int h = blockIdx.y, db = blockIdx.x * 16;
  int t = threadIdx.x, dp = t & 63, d0 = db + (t >> 6) * 4;
  float acc[4] = {0.f, 0.f, 0.f, 0.f};
  const float* kr = kpw + ((size_t)h * 64 + dp) * 512;
  const float* qr = qpw + ((size_t)h * 64 + d0) * 512;
  for (int r = 0; r < 512; r += 4) {
    float4 wk = *(const float4*)(kr + r);
    #pragma unroll
    for (int i = 0; i < 4; i++) {
      float4 wq = *(const float4*)(qr + i * 512 + r);
      acc[i] += wq.x * wk.x + wq.y * wk.y + wq.z * wk.z + wq.w * wk.w;
    }
  }
  #pragma unroll
  for (int i = 0; i < 4; i++)
    Ah[((size_t)h * 64 + d0 + i) * 64 + dp] = acc[i] * 0.044194173824159216f;
}

// ---- W'[h*64+d'][:] = sum_d A_h[h][d][d'] * Wq[h*64+d][:]  (bf16 into w3 Q rows)
//      bq2[h*64+d'] = sum_d bq[h*64+d] * A_h[h][d][d'] ----
__global__ __launch_bounds__(256) void k_wq(
    const float* __restrict__ Wq, const float* __restrict__ Ah,
    const float* __restrict__ bq, ushort_t* __restrict__ w3, float* __restrict__ bq2) {
  __shared__ float wq_s[64][65];
  __shared__ float ah_s[64][65];
  int h = blockIdx.y, ct = blockIdx.x;
  int t = threadIdx.x;
  #pragma unroll
  for (int i = 0; i < 16; i++) {
    int idx = i * 256 + t, r = idx >> 6, c = idx & 63;
    wq_s[r][c] = Wq[((size_t)h * 64 + r) * 1024 + ct * 64 + c];
    ah_s[r][c] = Ah[((size_t)h * 64 + r) * 64 + c];
  }
  __syncthreads();
  int dp = t >> 2, cg = (t & 3) * 16;
  float acc[16];
  #pragma unroll
  for (int j = 0; j < 16; j++) acc[j] = 0.f;
  for (int d = 0; d < 64; d++) {
    float a = ah_s[d][dp];
    #pragma unroll
    for (int j = 0; j < 16; j++) acc[j] += a * wq_s[d][cg + j];
  }
  ushort_t* orow = w3 + ((size_t)h * 64 + dp) * 1024 + ct * 64 + cg;
  #pragma unroll
  for (int j = 0; j < 16; j += 4) {
    unsigned long long pk = (unsigned long long)f2bf(acc[j])
                          | ((unsigned long long)f2bf(acc[j + 1]) << 16)
                          | ((unsigned long long)f2bf(acc[j + 2]) << 32)
                          | ((unsigned long long)f2bf(acc[j + 3]) << 48);
    *(unsigned long long*)(orow + j) = pk;
  }
  if (ct == 0 && t < 64) {
    float bsum = 0.f;
    for (int d = 0; d < 64; d++) bsum += bq[h * 64 + d] * ah_s[d][t];
    bq2[h * 64 + t] = bsum;
  }
}

// ---- V transpose: qkv V-cols -> vT[bh][64 d][2048 m] bf16 ----
__global__ void k_vT(const ushort_t* __restrict__ qkv, ushort_t* __restrict__ vT) {
  int bh = blockIdx.y, b = bh >> 4, h = bh & 15;
  int d = threadIdx.x >> 2;                       // 0..63
  int mc = blockIdx.x * 4 + (threadIdx.x & 3);    // 0..255
  int m0 = mc * 8;
  const ushort_t* src = qkv + ((size_t)(b * 2048 + m0)) * 3072 + 2048 + h * 64 + d;
  bf16x8 r;
  #pragma unroll
  for (int j = 0; j < 8; j++) r[j] = (short)src[(size_t)j * 3072];
  *(bf16x8*)(vT + ((size_t)(bh * 64 + d)) * 2048 + m0) = r;
}

// ---- QKV GEMM: C[4096][3072] = A[4096][1024] @ W[3072][1024]^T + bias ----
__global__ __launch_bounds__(256) void k_gemm_qkv(
    const ushort_t* __restrict__ A, const ushort_t* __restrict__ W,
    const float* __restrict__ bq, const float* __restrict__ bk,
    const float* __restrict__ bv, ushort_t* __restrict__ C) {
  __shared__ ushort_t Asm[128 * 32];
  __shared__ ushort_t Bsm[128 * 32];
  const int tid = threadIdx.x, w = tid >> 6, l = tid & 63, g = l >> 4, l15 = l & 15;
  const int mbase = blockIdx.x * 128, nbase = blockIdx.y * 128;
  const int wrow = (w >> 1) * 64, wcol = (w & 1) * 64;
  f32x4 zero4 = {0.f, 0.f, 0.f, 0.f};
  f32x4 acc[4][4];
  #pragma unroll
  for (int i = 0; i < 4; i++)
    #pragma unroll
    for (int j = 0; j < 4; j++) acc[i][j] = zero4;

  for (int kt = 0; kt < 32; ++kt) {
    __syncthreads();
    #pragma unroll
    for (int i = 0; i < 2; i++) {
      int inst = w * 2 + i;
      int r = inst * 16 + (l >> 2);
      int cs = (l & 3) ^ (r & 3);
      load_lds16(A + (size_t)(mbase + r) * 1024 + kt * 32 + cs * 8, &Asm[inst * 512]);
      load_lds16(W + (size_t)(nbase + r) * 1024 + kt * 32 + cs * 8, &Bsm[inst * 512]);
    }
    __syncthreads();
    bf16x8 a[4], bfr[4];
    #pragma unroll
    for (int rt = 0; rt < 4; rt++) {
      int r = wrow + rt * 16 + l15;
      a[rt] = *(const bf16x8*)(&Asm[r * 32 + ((g ^ (r & 3)) << 3)]);
    }
    #pragma unroll
    for (int ct = 0; ct < 4; ct++) {
      int r = wcol + ct * 16 + l15;
      bfr[ct] = *(const bf16x8*)(&Bsm[r * 32 + ((g ^ (r & 3)) << 3)]);
    }
    #pragma unroll
    for (int rt = 0; rt < 4; rt++)
      #pragma unroll
      for (int ct = 0; ct < 4; ct++)
        acc[rt][ct] = mfma16(a[rt], bfr[ct], acc[rt][ct]);
  }
  #pragma unroll
  for (int ct = 0; ct < 4; ct++) {
    int n = nbase + wcol + ct * 16 + l15;
    float bias = (n < 1024) ? bq[n] : (n < 2048 ? bk[n - 1024] : bv[n - 2048]);
    #pragma unroll
    for (int rt = 0; rt < 4; rt++)
      #pragma unroll
      for (int reg = 0; reg < 4; reg++) {
        int m = mbase + wrow + rt * 16 + g * 4 + reg;
        C[(size_t)m * 3072 + n] = f2bf(acc[rt][ct][reg] + bias);
      }
  }
}

// ---- flash attention, K=64: 4 waves x 32 q = 128 q/block, KVB=64, dbuf DMA ----
// P stays in registers: A-row permutation maps lane (g,l15) regs (mt,reg) to
// m = (mt>>1)*32 + g*8 + (mt&1)*4 + reg == the PV B-frag k-slots.
#define NEG_INF -1e30f
#define FENCE() asm volatile("" ::: "memory")
__global__ __launch_bounds__(256, 3) void k_attn(
    const ushort_t* __restrict__ qkv, const ushort_t* __restrict__ vT,
    const float* __restrict__ tab, const float* __restrict__ mask,
    float* __restrict__ out) {
  __shared__ ushort_t k_sm[2][64][64];    // 16 KB, phys chunk p holds global chunk p^f(m)
  __shared__ ushort_t vt_sm[2][64][64];   // 16 KB, same swizzle by d
  const int tid = threadIdx.x, w = tid >> 6, l = tid & 63, g = l >> 4, l15 = l & 15;
  const int e01 = l15 & 3, a0 = (l15 >> 2) & 1;
  const int lr = l >> 3, lc = l & 7;
  // 512 blocks: each XCD owns 4 bh x 16 q-blocks of 128 rows
  const int bid = blockIdx.x, xcd = bid & 7, slot = bid >> 3;
  const int bh = xcd * 4 + (slot & 3), qb = slot >> 2;
  const int b = bh >> 4, h = bh & 15;
  const int wrow = qb * 128 + w * 32;

  const ushort_t* kbase = qkv + 1024 + h * 64;  // + row*3072
  const ushort_t* vT_bh = vT + (size_t)bh * 64 * 2048;
  const float* tabh = tab + h * 4095 + 2047;
  const float* maskb = mask + b * 2048;

  auto stage = [&](int t, int bi) {
    int kvb = t * 64;
    #pragma unroll
    for (int ii = 0; ii < 2; ii++) {
      int m = w * 16 + ii * 8 + lr;
      int sc = lc ^ ((lr & 3) | (ii << 2));
      load_lds16(kbase + (size_t)(b * 2048 + kvb + m) * 3072 + sc * 8,
                 &k_sm[bi][w * 16 + ii * 8][0]);
    }
    #pragma unroll
    for (int ii = 0; ii < 2; ii++) {
      int d = w * 16 + ii * 8 + lr;
      int sc = lc ^ ((lr & 3) | (ii << 2));
      load_lds16(vT_bh + (size_t)d * 2048 + kvb + sc * 8,
                 &vt_sm[bi][w * 16 + ii * 8][0]);
    }
  };

  stage(0, 0);

  // qt fragments: 2 q-sets x 2 ksteps (K=64), 16 VGPR total
  bf16x8 qf[2][2];
  #pragma unroll
  for (int s = 0; s < 2; s++) {
    const ushort_t* qpr = qkv + (size_t)(b * 2048 + wrow + s * 16 + l15) * 3072 + h * 64 + g * 8;
    qf[s][0] = *(const bf16x8*)(qpr);
    qf[s][1] = *(const bf16x8*)(qpr + 32);
  }

  f32x4 zero4 = {0.f, 0.f, 0.f, 0.f};
  f32x4 ctx[2][4];
  float mrow[2], lrow[2];
  #pragma unroll
  for (int s = 0; s < 2; s++) {
    mrow[s] = NEG_INF; lrow[s] = 0.f;
    #pragma unroll
    for (int dt = 0; dt < 4; dt++) ctx[s][dt] = zero4;
  }

  for (int t = 0; t < 32; t++) {
    const int bi = t & 1;
    const int kvb = t * 64;
    if (t < 31) {
      stage(t + 1, bi ^ 1);
      asm volatile("s_waitcnt vmcnt(4)" ::: "memory");
    } else {
      asm volatile("s_waitcnt vmcnt(0)" ::: "memory");
    }
    __builtin_amdgcn_s_barrier();
    FENCE();

    // QK^T (swapped + row-permuted): ST[s][mt][reg] = S[q][m=kvb+(mt>>1)*32+g*8+(mt&1)*4+reg]
    f32x4 ST[2][4];
    #pragma unroll
    for (int s = 0; s < 2; s++)
      #pragma unroll
      for (int mt = 0; mt < 4; mt++) ST[s][mt] = zero4;
    #pragma unroll
    for (int ks = 0; ks < 2; ks++) {
      #pragma unroll
      for (int mt = 0; mt < 4; mt++) {
        int mr = (mt >> 1) * 32 + (l15 >> 2) * 8 + (mt & 1) * 4 + e01;  // permuted A-row
        int pc = (ks * 4 + g) ^ (e01 | (a0 << 2));
        bf16x8 af = *(const bf16x8*)(&k_sm[bi][mr][pc * 8]);
        ST[0][mt] = mfma16(af, qf[0][ks], ST[0][mt]);
        ST[1][mt] = mfma16(af, qf[1][ks], ST[1][mt]);
      }
    }

    // online softmax per lane (lane owns q = wrow+s*16+l15) + defer-max
    bf16x8 pf[2][2];
    #pragma unroll
    for (int s = 0; s < 2; s++) {
      const int q = wrow + s * 16 + l15;
      float sv[4][4];
      float rm = NEG_INF;
      #pragma unroll
      for (int mt = 0; mt < 4; mt++) {
        int mo = kvb + (mt >> 1) * 32 + g * 8 + (mt & 1) * 4;
        float4 mk = *(const float4*)(maskb + mo);
        const float* tq = tabh + mo - q;
        sv[mt][0] = ST[s][mt][0] + mk.x + tq[0];
        sv[mt][1] = ST[s][mt][1] + mk.y + tq[1];
        sv[mt][2] = ST[s][mt][2] + mk.z + tq[2];
        sv[mt][3] = ST[s][mt][3] + mk.w + tq[3];
        #pragma unroll
        for (int reg = 0; reg < 4; reg++) rm = fmaxf(rm, sv[mt][reg]);
      }
      rm = fmaxf(rm, __shfl_xor(rm, 16));
      rm = fmaxf(rm, __shfl_xor(rm, 32));
      if (__any(rm > mrow[s] + 8.0f)) {
        float mn = fmaxf(mrow[s], rm);
        float corr = __expf(mrow[s] - mn);
        mrow[s] = mn;
        lrow[s] *= corr;
        #pragma unroll
        for (int dt = 0; dt < 4; dt++)
          #pragma unroll
          for (int e = 0; e < 4; e++) ctx[s][dt][e] *= corr;
      }
      float pv[4][4], rs = 0.f;
      #pragma unroll
      for (int mt = 0; mt < 4; mt++)
        #pragma unroll
        for (int reg = 0; reg < 4; reg++) {
          pv[mt][reg] = __expf(sv[mt][reg] - mrow[s]);
          rs += pv[mt][reg];
        }
      rs += __shfl_xor(rs, 16);
      rs += __shfl_xor(rs, 32);
      lrow[s] += rs;
      union { unsigned u[4]; bf16x8 v; } pk0, pk1;
      pk0.u[0] = cvt_pk_bf16(pv[0][0], pv[0][1]);
      pk0.u[1] = cvt_pk_bf16(pv[0][2], pv[0][3]);
      pk0.u[2] = cvt_pk_bf16(pv[1][0], pv[1][1]);
      pk0.u[3] = cvt_pk_bf16(pv[1][2], pv[1][3]);
      pk1.u[0] = cvt_pk_bf16(pv[2][0], pv[2][1]);
      pk1.u[1] = cvt_pk_bf16(pv[2][2], pv[2][3]);
      pk1.u[2] = cvt_pk_bf16(pv[3][0], pv[3][1]);
      pk1.u[3] = cvt_pk_bf16(pv[3][2], pv[3][3]);
      pf[s][0] = pk0.v;
      pf[s][1] = pk1.v;
    }

    // PV: ctx[s][dt] += V^T-frag x P-frag (P in regs)
    #pragma unroll
    for (int kp = 0; kp < 2; kp++) {
      #pragma unroll
      for (int dt = 0; dt < 4; dt++) {
        int d = dt * 16 + l15;
        int pc = (kp * 4 + g) ^ (e01 | (((l15 >> 3) & 1) << 2));
        bf16x8 vf = *(const bf16x8*)(&vt_sm[bi][d][pc * 8]);
        ctx[0][dt] = mfma16(vf, pf[0][kp], ctx[0][dt]);
        ctx[1][dt] = mfma16(vf, pf[1][kp], ctx[1][dt]);
      }
    }

    FENCE();
    __builtin_amdgcn_s_barrier();
    FENCE();
  }

  #pragma unroll
  for (int s = 0; s < 2; s++) {
    float inv = 1.0f / lrow[s];
    int r = wrow + s * 16 + l15;
    float* op = out + ((size_t)(b * 2048 + r)) * 1024 + h * 64 + g * 4;
    #pragma unroll
    for (int dt = 0; dt < 4; dt++) {
      float4 o = {ctx[s][dt][0] * inv, ctx[s][dt][1] * inv, ctx[s][dt][2] * inv, ctx[s][dt][3] * inv};
      *(float4*)(op + dt * 16) = o;
    }
  }
}

extern "C" void kernel_launch(void* const* d_in, const int* in_sizes, int n_in,
                              void* d_out, int out_size, void* d_ws, size_t ws_size,
                              hipStream_t stream) {
  const float* hidden = (const float*)d_in[0];
  const float* maskp  = (const float*)d_in[1];
  const float* Wq     = (const float*)d_in[2];
  const float* bq     = (const float*)d_in[3];
  const float* Wk     = (const float*)d_in[4];
  const float* bk     = (const float*)d_in[5];
  const float* Wv     = (const float*)d_in[6];
  const float* bv     = (const float*)d_in[7];
  const float* qpw    = (const float*)d_in[8];
  const float* kpw    = (const float*)d_in[9];
  const float* coef   = (const float*)d_in[10];

  char* ws = (char*)d_ws;
  float*    tab  = (float*)(ws);                      // 262,144
  ushort_t* hb   = (ushort_t*)(ws + 262144);          // 8,388,608 (reused as vT after GEMM)
  ushort_t* w3   = (ushort_t*)(ws + 8650752);         // 6,291,456
  float*    Ah   = (float*)(ws + 14942208);           // 16*64*64*4 = 262,144
  float*    bq2  = (float*)(ws + 15204352);           // 4,096
  ushort_t* qkv  = (ushort_t*)(ws + 15208448);        // 4096*3072*2 = 25,165,824 (end 40,374,272)
  ushort_t* vTb  = hb;                                // 8 MB, hb dead after GEMM

  k_bias_tab<<<dim3(16, 16), 256, 0, stream>>>(coef, tab);
  k_cvt<<<4096, 256, 0, stream>>>(hidden, hb, 4194304);
  k_cvt<<<1024, 256, 0, stream>>>(Wk, w3 + 1048576, 1048576);
  k_cvt<<<1024, 256, 0, stream>>>(Wv, w3 + 2097152, 1048576);
  k_ah<<<dim3(4, 16), 256, 0, stream>>>(qpw, kpw, Ah);
  k_wq<<<dim3(16, 16), 256, 0, stream>>>(Wq, Ah, bq, w3, bq2);
  k_gemm_qkv<<<dim3(32, 24), 256, 0, stream>>>(hb, w3, bq2, bk, bv, qkv);
  k_vT<<<dim3(64, 32), 256, 0, stream>>>(qkv, vTb);
  k_attn<<<dim3(512), 256, 0, stream>>>(qkv, vTb, tab, maskp, (float*)d_out);
}